// Round 5
// baseline (522.983 us; speedup 1.0000x reference)
//
#include <hip/hip_runtime.h>
#include <math.h>

// Problem constants (fixed shape)
#define B 256
#define W 512
#define F 512
#define N 512

// -----------------------------------------------------------------------------
// Kernel A: t = x^T @ wvec, f-quarter split.
// grid = B*4 (block (b,fq) owns ALL 512 words x 128 f-cols), 512 threads.
// 4 blocks/CU x 8 waves = 32 waves/CU -> proven ~5+ TB/s HBM streaming rate.
// Thread (wg = tid>>5, fc = tid&31): words [wg*32,+32), f-col fq*128+fc*4.
// Block-complete result -> tbuf[b][fq*128 : +128] in d_ws (512 KB total).
// -----------------------------------------------------------------------------
__global__ __launch_bounds__(512, 8) void tpart_kernel(
    const float* __restrict__ x,
    const float* __restrict__ wvec,
    float* __restrict__ tbuf)
{
    const int blk = blockIdx.x;
    const int b   = blk >> 2;
    const int fq  = blk & 3;
    const int tid = threadIdx.x;
    const int wg  = tid >> 5;    // 0..15, 32-word group
    const int fc  = tid & 31;    // float4 column within the 128-f slice

    __shared__ float s_w[W];
    __shared__ float s_part[16][128];

    s_w[tid] = wvec[tid];        // W == 512 == blockDim
    __syncthreads();

    const float* xb = x + (size_t)b * W * F + fq * 128 + fc * 4;
    float4 acc = make_float4(0.f, 0.f, 0.f, 0.f);
#pragma unroll 8
    for (int i = 0; i < 32; ++i) {
        const float4 xv = *(const float4*)(xb + (size_t)(wg * 32 + i) * F);
        const float  ww = s_w[wg * 32 + i];
        acc.x += xv.x * ww; acc.y += xv.y * ww;
        acc.z += xv.z * ww; acc.w += xv.w * ww;
    }
    *(float4*)&s_part[wg][fc * 4] = acc;
    __syncthreads();

    if (tid < 128) {
        float s = 0.f;
#pragma unroll
        for (int j = 0; j < 16; ++j) s += s_part[j][tid];
        tbuf[(size_t)b * N + fq * 128 + tid] = s;
    }
}

// -----------------------------------------------------------------------------
// Kernel C: t -> Q -> r -> online-softmax attention -> out.  grid = B, 1024 thr
// (16 waves).  Reads t from tbuf (d_ws).  Attention inner loop: 4-word batches,
// explicit ping-pong register prefetch (fully unrolled, compile-time buffer
// parity) so ~8 float4 loads stay in flight per thread during shuffle/softmax —
// round-3 evidence (VGPR=64, 10.7 GB/s/CU) showed the compiler otherwise
// serializes to ~1 outstanding load.
// -----------------------------------------------------------------------------
__global__ __launch_bounds__(1024, 4) void attn_kernel(
    const float* __restrict__ x,
    const float* __restrict__ Wq,
    const float* __restrict__ Wk,
    const float* __restrict__ Wv,
    const float* __restrict__ tbuf,
    float* __restrict__ out)
{
    const int b    = blockIdx.x;
    const int tid  = threadIdx.x;
    const int lane = tid & 63;
    const int wv   = tid >> 6;    // 0..15
    const int f5   = tid & 511;   // 0..511
    const int half = tid >> 9;    // 0..1

    __shared__ float s_c[16][F];    // per-wave c partials (32 KB)
    __shared__ float s_p2[2][F];    // half-split combine buffer
    __shared__ float s_t[F];
    __shared__ float s_q[N];
    __shared__ float s_r[F];
    __shared__ float s_m[16];
    __shared__ float s_l[16];
    __shared__ float s_cf[F];

    const float* xb = x + (size_t)b * W * F;

    // ---------------- Phase 0: stage t, Q = t@Wq, r = scale*Wk@Q ----------
    if (tid < F) s_t[tid] = tbuf[(size_t)b * N + tid];
    __syncthreads();

    {
        const int fb = half * 256;
        float q0 = 0.f, q1 = 0.f, q2 = 0.f, q3 = 0.f;
#pragma unroll 4
        for (int f = 0; f < 256; f += 4) {
            q0 += s_t[fb + f + 0] * Wq[(size_t)(fb + f + 0) * N + f5];
            q1 += s_t[fb + f + 1] * Wq[(size_t)(fb + f + 1) * N + f5];
            q2 += s_t[fb + f + 2] * Wq[(size_t)(fb + f + 2) * N + f5];
            q3 += s_t[fb + f + 3] * Wq[(size_t)(fb + f + 3) * N + f5];
        }
        s_p2[half][f5] = (q0 + q1) + (q2 + q3);
    }
    __syncthreads();
    if (tid < N) s_q[tid] = s_p2[0][tid] + s_p2[1][tid];
    __syncthreads();

    {
        const float4* wkrow = (const float4*)(Wk + (size_t)f5 * N + half * 256);
        const float4* qv4   = (const float4*)&s_q[half * 256];
        float r0 = 0.f, r1 = 0.f, r2 = 0.f, r3 = 0.f;
#pragma unroll 8
        for (int n4 = 0; n4 < 64; ++n4) {
            const float4 kv = wkrow[n4];
            const float4 qq = qv4[n4];
            r0 += kv.x * qq.x; r1 += kv.y * qq.y;
            r2 += kv.z * qq.z; r3 += kv.w * qq.w;
        }
        s_p2[half][f5] = (r0 + r1) + (r2 + r3);
    }
    __syncthreads();
    if (tid < F) s_r[tid] = (s_p2[0][tid] + s_p2[1][tid]) * 0.04419417382415922f;
    __syncthreads();

    // ---------------- Phase 1: online softmax + c, prefetch-pipelined ------
    const float4 r0 = *(const float4*)&s_r[lane * 4];
    const float4 r1 = *(const float4*)&s_r[256 + lane * 4];

    float m = -INFINITY, l = 0.f;
    float4 c0 = make_float4(0.f, 0.f, 0.f, 0.f);
    float4 c1 = make_float4(0.f, 0.f, 0.f, 0.f);

    // wave wv owns words [wv*32, +32): 8 batches of 4 words, ping-pong buffers
    float4 xa0[2][4], xa1[2][4];
    {
        const float* row = xb + (size_t)(wv * 32) * F;
#pragma unroll
        for (int j = 0; j < 4; ++j) {
            xa0[0][j] = *(const float4*)(row + (size_t)j * F + lane * 4);
            xa1[0][j] = *(const float4*)(row + (size_t)j * F + 256 + lane * 4);
        }
    }

#pragma unroll
    for (int t = 0; t < 8; ++t) {
        const int cur = t & 1;        // compile-time under full unroll
        const int nxt = cur ^ 1;

        if (t < 7) {  // issue next batch's loads BEFORE consuming current
            const float* rown = xb + (size_t)(wv * 32 + (t + 1) * 4) * F;
#pragma unroll
            for (int j = 0; j < 4; ++j) {
                xa0[nxt][j] = *(const float4*)(rown + (size_t)j * F + lane * 4);
                xa1[nxt][j] = *(const float4*)(rown + (size_t)j * F + 256 + lane * 4);
            }
        }

        float d[4];
#pragma unroll
        for (int j = 0; j < 4; ++j) {
            d[j] = xa0[cur][j].x * r0.x + xa0[cur][j].y * r0.y
                 + xa0[cur][j].z * r0.z + xa0[cur][j].w * r0.w
                 + xa1[cur][j].x * r1.x + xa1[cur][j].y * r1.y
                 + xa1[cur][j].z * r1.z + xa1[cur][j].w * r1.w;
        }

#pragma unroll
        for (int off = 32; off >= 1; off >>= 1) {
#pragma unroll
            for (int j = 0; j < 4; ++j)
                d[j] += __shfl_xor(d[j], off, 64);
        }

        const float mb = fmaxf(fmaxf(d[0], d[1]), fmaxf(d[2], d[3]));
        const float mn = fmaxf(m, mb);
        const float sc = __expf(m - mn);   // m=-inf on first batch -> sc=0

        float p[4];
#pragma unroll
        for (int j = 0; j < 4; ++j) p[j] = __expf(d[j] - mn);
        l = l * sc + ((p[0] + p[1]) + (p[2] + p[3]));

        float ax = c0.x * sc, ay = c0.y * sc, az = c0.z * sc, aw = c0.w * sc;
#pragma unroll
        for (int j = 0; j < 4; ++j) {
            ax += p[j] * xa0[cur][j].x; ay += p[j] * xa0[cur][j].y;
            az += p[j] * xa0[cur][j].z; aw += p[j] * xa0[cur][j].w;
        }
        c0 = make_float4(ax, ay, az, aw);

        ax = c1.x * sc; ay = c1.y * sc; az = c1.z * sc; aw = c1.w * sc;
#pragma unroll
        for (int j = 0; j < 4; ++j) {
            ax += p[j] * xa1[cur][j].x; ay += p[j] * xa1[cur][j].y;
            az += p[j] * xa1[cur][j].z; aw += p[j] * xa1[cur][j].w;
        }
        c1 = make_float4(ax, ay, az, aw);

        m = mn;
    }

    *(float4*)&s_c[wv][lane * 4]       = c0;
    *(float4*)&s_c[wv][256 + lane * 4] = c1;
    if (lane == 0) { s_m[wv] = m; s_l[wv] = l; }
    __syncthreads();

    // ---------------- Phase 2: merge 16 waves + normalize + out GEMV -------
    float M = -INFINITY;
#pragma unroll
    for (int j = 0; j < 16; ++j) M = fmaxf(M, s_m[j]);
    float L = 0.f;
    float alpha[16];
#pragma unroll
    for (int j = 0; j < 16; ++j) {
        alpha[j] = __expf(s_m[j] - M);
        L += alpha[j] * s_l[j];
    }
    const float invL = 1.f / L;

    {
        float cp = 0.f;
#pragma unroll
        for (int j = 0; j < 8; ++j) cp += alpha[half * 8 + j] * s_c[half * 8 + j][f5];
        s_p2[half][f5] = cp;
    }
    __syncthreads();
    if (tid < F) s_cf[tid] = (s_p2[0][tid] + s_p2[1][tid]) * invL;
    __syncthreads();

    {
        const int fb = half * 256;
        float o0 = 0.f, o1 = 0.f, o2 = 0.f, o3 = 0.f;
#pragma unroll 4
        for (int f = 0; f < 256; f += 4) {
            o0 += s_cf[fb + f + 0] * Wv[(size_t)(fb + f + 0) * N + f5];
            o1 += s_cf[fb + f + 1] * Wv[(size_t)(fb + f + 1) * N + f5];
            o2 += s_cf[fb + f + 2] * Wv[(size_t)(fb + f + 2) * N + f5];
            o3 += s_cf[fb + f + 3] * Wv[(size_t)(fb + f + 3) * N + f5];
        }
        s_p2[half][f5] = (o0 + o1) + (o2 + o3);
    }
    __syncthreads();
    if (tid < N) out[(size_t)b * N + tid] = s_p2[0][tid] + s_p2[1][tid];
}

// -----------------------------------------------------------------------------
// Launcher.  Two kernels; t lives in d_ws (512 KB) between them.
// -----------------------------------------------------------------------------
extern "C" void kernel_launch(void* const* d_in, const int* in_sizes, int n_in,
                              void* d_out, int out_size, void* d_ws, size_t ws_size,
                              hipStream_t stream)
{
    const float* x    = (const float*)d_in[0];
    const float* Wk   = (const float*)d_in[1];
    const float* Wq   = (const float*)d_in[2];
    const float* Wv   = (const float*)d_in[3];
    const float* wvec = (const float*)d_in[4];
    float* out  = (float*)d_out;
    float* tbuf = (float*)d_ws;

    tpart_kernel<<<B * 4, 512, 0, stream>>>(x, wvec, tbuf);
    attn_kernel<<<B, 1024, 0, stream>>>(x, Wq, Wk, Wv, tbuf, out);
}

// Round 6
// 476.723 us; speedup vs baseline: 1.0970x; 1.0970x over previous
//
#include <hip/hip_runtime.h>
#include <math.h>

// Problem constants (fixed shape)
#define B 256
#define W 512
#define F 512
#define N 512
#define GPART 4            // partial blocks per sample in kernel A
#define WPG (W / GPART)    // 128 words per A-block

// -----------------------------------------------------------------------------
// Kernel A (R0-proven, verbatim): t partials.  grid = B*4, 512 thr,
// 4 blocks/CU -> 32 waves/CU, fully contiguous 256 KB x-read per block.
// ~50 us measured (R0/R1 fits).
// -----------------------------------------------------------------------------
__global__ __launch_bounds__(512) void tpart_kernel(
    const float* __restrict__ x,
    const float* __restrict__ wvec,
    float* __restrict__ t_part)
{
    const int blk = blockIdx.x;
    const int g   = blk & (GPART - 1);
    const int b   = blk >> 2;
    const int tid = threadIdx.x;
    const int ws  = tid >> 7;     // 0..3
    const int f4  = tid & 127;

    __shared__ float s_w[WPG];
    __shared__ float s_part[4][F];

    if (tid < WPG) s_w[tid] = wvec[g * WPG + tid];
    __syncthreads();

    const float* xb = x + (size_t)b * W * F + (size_t)(g * WPG + ws * 32) * F;
    float4 acc = make_float4(0.f, 0.f, 0.f, 0.f);
#pragma unroll 8
    for (int i = 0; i < 32; ++i) {
        const float4 xv = *(const float4*)(xb + (size_t)i * F + f4 * 4);
        const float  ww = s_w[ws * 32 + i];
        acc.x += xv.x * ww; acc.y += xv.y * ww;
        acc.z += xv.z * ww; acc.w += xv.w * ww;
    }
    *(float4*)&s_part[ws][f4 * 4] = acc;
    __syncthreads();

    const float t = (s_part[0][tid] + s_part[1][tid])
                  + (s_part[2][tid] + s_part[3][tid]);
    t_part[(size_t)blk * F + tid] = t;
}

// -----------------------------------------------------------------------------
// Kernel B (R0-proven, verbatim): reduce t partials, Q = t@Wq, r = scale*Wk@Q.
// grid = B, 512 threads.  ~20 us.
// -----------------------------------------------------------------------------
__global__ __launch_bounds__(512) void qr_kernel(
    const float* __restrict__ t_part,
    const float* __restrict__ Wq,
    const float* __restrict__ Wk,
    float* __restrict__ r_out)
{
    __shared__ float s_t[F];
    __shared__ float s_q[N];
    const int b = blockIdx.x, tid = threadIdx.x;

    float t = 0.f;
#pragma unroll
    for (int g = 0; g < GPART; ++g)
        t += t_part[((size_t)b * GPART + g) * F + tid];
    s_t[tid] = t;
    __syncthreads();

    float q0 = 0.f, q1 = 0.f, q2 = 0.f, q3 = 0.f;
#pragma unroll 4
    for (int f = 0; f < F; f += 4) {
        q0 += s_t[f + 0] * Wq[(size_t)(f + 0) * N + tid];
        q1 += s_t[f + 1] * Wq[(size_t)(f + 1) * N + tid];
        q2 += s_t[f + 2] * Wq[(size_t)(f + 2) * N + tid];
        q3 += s_t[f + 3] * Wq[(size_t)(f + 3) * N + tid];
    }
    s_q[tid] = (q0 + q1) + (q2 + q3);
    __syncthreads();

    const float4* wkrow = (const float4*)(Wk + (size_t)tid * N);
    float r0 = 0.f, r1 = 0.f, r2 = 0.f, r3 = 0.f;
#pragma unroll 8
    for (int n4 = 0; n4 < N / 4; ++n4) {
        const float4 kv = wkrow[n4];
        const float4 qv = *(const float4*)&s_q[n4 * 4];
        r0 += kv.x * qv.x; r1 += kv.y * qv.y;
        r2 += kv.z * qv.z; r3 += kv.w * qv.w;
    }
    r_out[(size_t)b * F + tid] =
        ((r0 + r1) + (r2 + r3)) * 0.04419417382415922f;  // 1/sqrt(512)
}

// -----------------------------------------------------------------------------
// Kernel C': attention PARTIAL.  grid = B*4 (block (b,wq) owns words
// [wq*128, +128)), 512 thr = 8 waves, __launch_bounds__(512,8) -> VGPR<=64
// -> 4 blocks/CU = 32 waves/CU (the occupancy every fast kernel here has had;
// all 1-block/CU attention variants measured 140-195 us).
// Lean R0-style batch-2 body.  Block-merges its 8 waves and writes an
// UNNORMALIZED partial (m_blk, l_blk, c_blk[512]) to workspace.
// -----------------------------------------------------------------------------
__global__ __launch_bounds__(512, 8) void attn_part_kernel(
    const float* __restrict__ x,
    const float* __restrict__ r_in,
    float* __restrict__ m_out,     // [B*4]
    float* __restrict__ l_out,     // [B*4]
    float* __restrict__ c_out)     // [B*4][F]
{
    const int blk  = blockIdx.x;
    const int b    = blk >> 2;
    const int wq   = blk & 3;
    const int tid  = threadIdx.x;
    const int lane = tid & 63;
    const int wv   = tid >> 6;     // 0..7

    __shared__ float s_c[8][F];
    __shared__ float s_m[8];
    __shared__ float s_l[8];

    const float* xb = x + (size_t)b * W * F + (size_t)(wq * 128) * F;
    const float* rb = r_in + (size_t)b * F;
    const float4 r0 = *(const float4*)(rb + lane * 4);
    const float4 r1 = *(const float4*)(rb + 256 + lane * 4);

    float m = -INFINITY, l = 0.f;
    float4 c0 = make_float4(0.f, 0.f, 0.f, 0.f);
    float4 c1 = make_float4(0.f, 0.f, 0.f, 0.f);

    // wave wv owns words [wv*16, +16) of this block's 128; 2 words/iter
#pragma unroll 2
    for (int i = 0; i < 16; i += 2) {
        const float* rowA = xb + (size_t)(wv * 16 + i) * F;
        const float* rowB = rowA + F;
        const float4 a0 = *(const float4*)(rowA + lane * 4);
        const float4 a1 = *(const float4*)(rowA + 256 + lane * 4);
        const float4 b0 = *(const float4*)(rowB + lane * 4);
        const float4 b1 = *(const float4*)(rowB + 256 + lane * 4);

        float dA = a0.x * r0.x + a0.y * r0.y + a0.z * r0.z + a0.w * r0.w
                 + a1.x * r1.x + a1.y * r1.y + a1.z * r1.z + a1.w * r1.w;
        float dB = b0.x * r0.x + b0.y * r0.y + b0.z * r0.z + b0.w * r0.w
                 + b1.x * r1.x + b1.y * r1.y + b1.z * r1.z + b1.w * r1.w;
#pragma unroll
        for (int off = 32; off >= 1; off >>= 1) {
            dA += __shfl_xor(dA, off, 64);
            dB += __shfl_xor(dB, off, 64);
        }

        float mn = fmaxf(m, dA);
        float sc = __expf(m - mn);
        float p  = __expf(dA - mn);
        l = l * sc + p;
        c0.x = c0.x * sc + p * a0.x; c0.y = c0.y * sc + p * a0.y;
        c0.z = c0.z * sc + p * a0.z; c0.w = c0.w * sc + p * a0.w;
        c1.x = c1.x * sc + p * a1.x; c1.y = c1.y * sc + p * a1.y;
        c1.z = c1.z * sc + p * a1.z; c1.w = c1.w * sc + p * a1.w;
        m = mn;

        mn = fmaxf(m, dB);
        sc = __expf(m - mn);
        p  = __expf(dB - mn);
        l = l * sc + p;
        c0.x = c0.x * sc + p * b0.x; c0.y = c0.y * sc + p * b0.y;
        c0.z = c0.z * sc + p * b0.z; c0.w = c0.w * sc + p * b0.w;
        c1.x = c1.x * sc + p * b1.x; c1.y = c1.y * sc + p * b1.y;
        c1.z = c1.z * sc + p * b1.z; c1.w = c1.w * sc + p * b1.w;
        m = mn;
    }

    *(float4*)&s_c[wv][lane * 4]       = c0;
    *(float4*)&s_c[wv][256 + lane * 4] = c1;
    if (lane == 0) { s_m[wv] = m; s_l[wv] = l; }
    __syncthreads();

    // block-level merge of 8 waves -> unnormalized partial relative to M_blk
    float M = -INFINITY;
#pragma unroll
    for (int j = 0; j < 8; ++j) M = fmaxf(M, s_m[j]);
    float L = 0.f;
    float alpha[8];
#pragma unroll
    for (int j = 0; j < 8; ++j) {
        alpha[j] = __expf(s_m[j] - M);
        L += alpha[j] * s_l[j];
    }

    float cb = 0.f;
#pragma unroll
    for (int j = 0; j < 8; ++j) cb += alpha[j] * s_c[j][tid];
    c_out[(size_t)blk * F + tid] = cb;
    if (tid == 0) { m_out[blk] = M; l_out[blk] = L; }
}

// -----------------------------------------------------------------------------
// Kernel D: merge 4 partials per sample + out = cf@Wv.  grid = B, 512 thr.
// Reads 4*(m,l) scalars + 4 coalesced c rows, alpha-combines, GEMV Wv. ~15 us.
// -----------------------------------------------------------------------------
__global__ __launch_bounds__(512) void merge_out_kernel(
    const float* __restrict__ m_in,
    const float* __restrict__ l_in,
    const float* __restrict__ c_in,
    const float* __restrict__ Wv,
    float* __restrict__ out)
{
    __shared__ float s_cf[F];
    const int b = blockIdx.x, tid = threadIdx.x;

    float m4[4], l4[4];
#pragma unroll
    for (int j = 0; j < 4; ++j) {
        m4[j] = m_in[b * 4 + j];
        l4[j] = l_in[b * 4 + j];
    }
    float M = fmaxf(fmaxf(m4[0], m4[1]), fmaxf(m4[2], m4[3]));
    float L = 0.f;
    float alpha[4];
#pragma unroll
    for (int j = 0; j < 4; ++j) {
        alpha[j] = __expf(m4[j] - M);
        L += alpha[j] * l4[j];
    }
    const float invL = 1.f / L;

    float cf = 0.f;
#pragma unroll
    for (int j = 0; j < 4; ++j)
        cf += alpha[j] * c_in[((size_t)b * 4 + j) * F + tid];
    s_cf[tid] = cf * invL;
    __syncthreads();

    float o0 = 0.f, o1 = 0.f, o2 = 0.f, o3 = 0.f;
#pragma unroll 4
    for (int f = 0; f < F; f += 4) {
        o0 += s_cf[f + 0] * Wv[(size_t)(f + 0) * N + tid];
        o1 += s_cf[f + 1] * Wv[(size_t)(f + 1) * N + tid];
        o2 += s_cf[f + 2] * Wv[(size_t)(f + 2) * N + tid];
        o3 += s_cf[f + 3] * Wv[(size_t)(f + 3) * N + tid];
    }
    out[(size_t)b * N + tid] = (o0 + o1) + (o2 + o3);
}

// -----------------------------------------------------------------------------
// Launcher.  ws layout (floats):
//   t_part : B*4*F   (2 MB)
//   r      : B*F     (512 KB)
//   m,l    : B*4 each (8 KB)
//   c_part : B*4*F   (2 MB)
// No buffer is both read and written by the same kernel (replay-safe).
// -----------------------------------------------------------------------------
extern "C" void kernel_launch(void* const* d_in, const int* in_sizes, int n_in,
                              void* d_out, int out_size, void* d_ws, size_t ws_size,
                              hipStream_t stream)
{
    const float* x    = (const float*)d_in[0];
    const float* Wk   = (const float*)d_in[1];
    const float* Wq   = (const float*)d_in[2];
    const float* Wv   = (const float*)d_in[3];
    const float* wvec = (const float*)d_in[4];
    float* out    = (float*)d_out;

    float* t_part = (float*)d_ws;
    float* r      = t_part + (size_t)B * 4 * F;
    float* m_part = r + (size_t)B * F;
    float* l_part = m_part + (size_t)B * 4;
    float* c_part = l_part + (size_t)B * 4;

    tpart_kernel<<<B * 4, 512, 0, stream>>>(x, wvec, t_part);
    qr_kernel<<<B, 512, 0, stream>>>(t_part, Wq, Wk, r);
    attn_part_kernel<<<B * 4, 512, 0, stream>>>(x, r, m_part, l_part, c_part);
    merge_out_kernel<<<B, 512, 0, stream>>>(m_part, l_part, c_part, Wv, out);
}

// Round 7
// 428.839 us; speedup vs baseline: 1.2195x; 1.1117x over previous
//
#include <hip/hip_runtime.h>
#include <math.h>

// Problem constants (fixed shape)
#define B 256
#define W 512
#define F 512
#define N 512
#define NWAVE 16   // 1024 threads = 16 waves = 4 waves/SIMD

// Non-temporal float4 load: nt bit -> no L3 allocate / evict-first.
// Theory under test (R7): L3-hit BW (~2.75 TB/s measured R2/R3) is BELOW the
// cold-HBM stream rate (~5.4-6.7 TB/s).  x has no cross-iteration reuse value,
// so keeping it OUT of L3 should let both x passes run at HBM rate.
typedef float v4f __attribute__((ext_vector_type(4)));
__device__ __forceinline__ float4 ldnt4(const float* p) {
    v4f v = __builtin_nontemporal_load((const v4f*)p);
    return make_float4(v.x, v.y, v.z, v.w);
}

// -----------------------------------------------------------------------------
// Fully fused per-sample kernel — R3 structure VERBATIM except all x loads are
// non-temporal.  grid = B, 1024 threads (16 waves).
// -----------------------------------------------------------------------------
__global__ __launch_bounds__(1024, 4) void fused_attn_kernel(
    const float* __restrict__ x,
    const float* __restrict__ Wq,
    const float* __restrict__ Wk,
    const float* __restrict__ Wv,
    const float* __restrict__ wvec,
    float* __restrict__ out)
{
    const int b    = blockIdx.x;
    const int tid  = threadIdx.x;
    const int lane = tid & 63;
    const int wv   = tid >> 6;    // 0..15
    const int f5   = tid & 511;   // 0..511
    const int half = tid >> 9;    // 0..1

    __shared__ float s_w[W];           // staged wvec
    __shared__ float s_c[NWAVE][F];    // per-wave partials (t in ph1, c in ph3)
    __shared__ float s_p2[2][F];       // half-split combine buffer (reused 4x)
    __shared__ float s_t[F];
    __shared__ float s_q[N];
    __shared__ float s_r[F];
    __shared__ float s_m[NWAVE];
    __shared__ float s_l[NWAVE];
    __shared__ float s_cf[F];

    const float* xb = x + (size_t)b * W * F;

    // ---------------- Phase 1: t[f] = sum_w x[w,f]*wvec[w] ----------------
    if (tid < W) s_w[tid] = wvec[tid];
    __syncthreads();

    {
        float4 t0 = make_float4(0.f, 0.f, 0.f, 0.f);
        float4 t1 = make_float4(0.f, 0.f, 0.f, 0.f);
        const float* base = xb + (size_t)(wv * 32) * F;
#pragma unroll 2
        for (int i = 0; i < 32; i += 4) {
            float4 a0[4], a1[4];
#pragma unroll
            for (int j = 0; j < 4; ++j) {
                a0[j] = ldnt4(base + (size_t)(i + j) * F + lane * 4);
                a1[j] = ldnt4(base + (size_t)(i + j) * F + 256 + lane * 4);
            }
#pragma unroll
            for (int j = 0; j < 4; ++j) {
                const float ww = s_w[wv * 32 + i + j];
                t0.x += a0[j].x * ww; t0.y += a0[j].y * ww;
                t0.z += a0[j].z * ww; t0.w += a0[j].w * ww;
                t1.x += a1[j].x * ww; t1.y += a1[j].y * ww;
                t1.z += a1[j].z * ww; t1.w += a1[j].w * ww;
            }
        }
        *(float4*)&s_c[wv][lane * 4]       = t0;
        *(float4*)&s_c[wv][256 + lane * 4] = t1;
    }
    __syncthreads();

    {   // two-stage 16-partial reduce
        float tp = 0.f;
#pragma unroll
        for (int j = 0; j < 8; ++j) tp += s_c[half * 8 + j][f5];
        s_p2[half][f5] = tp;
    }
    __syncthreads();
    if (tid < F) s_t[tid] = s_p2[0][tid] + s_p2[1][tid];
    __syncthreads();

    // ---------------- Phase 2: Q = t@Wq, r = scale * Wk@Q (half-split) ----
    {
        const int fb = half * 256;
        float q0 = 0.f, q1 = 0.f, q2 = 0.f, q3 = 0.f;
#pragma unroll 4
        for (int f = 0; f < 256; f += 4) {
            q0 += s_t[fb + f + 0] * Wq[(size_t)(fb + f + 0) * N + f5];
            q1 += s_t[fb + f + 1] * Wq[(size_t)(fb + f + 1) * N + f5];
            q2 += s_t[fb + f + 2] * Wq[(size_t)(fb + f + 2) * N + f5];
            q3 += s_t[fb + f + 3] * Wq[(size_t)(fb + f + 3) * N + f5];
        }
        s_p2[half][f5] = (q0 + q1) + (q2 + q3);
    }
    __syncthreads();
    if (tid < N) s_q[tid] = s_p2[0][tid] + s_p2[1][tid];
    __syncthreads();

    {
        const float4* wkrow = (const float4*)(Wk + (size_t)f5 * N + half * 256);
        const float4* qv4   = (const float4*)&s_q[half * 256];
        float r0 = 0.f, r1 = 0.f, r2 = 0.f, r3 = 0.f;
#pragma unroll 8
        for (int n4 = 0; n4 < 64; ++n4) {
            const float4 kv = wkrow[n4];
            const float4 qq = qv4[n4];
            r0 += kv.x * qq.x; r1 += kv.y * qq.y;
            r2 += kv.z * qq.z; r3 += kv.w * qq.w;
        }
        s_p2[half][f5] = (r0 + r1) + (r2 + r3);
    }
    __syncthreads();
    if (tid < F) s_r[tid] = (s_p2[0][tid] + s_p2[1][tid]) * 0.04419417382415922f;
    __syncthreads();

    // ---------------- Phase 3: online softmax + c accumulation ------------
    const float4 r0 = *(const float4*)&s_r[lane * 4];
    const float4 r1 = *(const float4*)&s_r[256 + lane * 4];

    float m = -INFINITY, l = 0.f;
    float4 c0 = make_float4(0.f, 0.f, 0.f, 0.f);
    float4 c1 = make_float4(0.f, 0.f, 0.f, 0.f);

    // wave wv owns words [wv*32, wv*32+32): 4 batches of 8 words
#pragma unroll 2
    for (int t = 0; t < 4; ++t) {
        const float* row = xb + (size_t)(wv * 32 + t * 8) * F;

        float4 xa0[8], xa1[8];
#pragma unroll
        for (int j = 0; j < 8; ++j) {
            xa0[j] = ldnt4(row + (size_t)j * F + lane * 4);
            xa1[j] = ldnt4(row + (size_t)j * F + 256 + lane * 4);
        }

        float d[8];
#pragma unroll
        for (int j = 0; j < 8; ++j) {
            d[j] = xa0[j].x * r0.x + xa0[j].y * r0.y
                 + xa0[j].z * r0.z + xa0[j].w * r0.w
                 + xa1[j].x * r1.x + xa1[j].y * r1.y
                 + xa1[j].z * r1.z + xa1[j].w * r1.w;
        }

#pragma unroll
        for (int off = 32; off >= 1; off >>= 1) {
#pragma unroll
            for (int j = 0; j < 8; ++j)
                d[j] += __shfl_xor(d[j], off, 64);
        }

        const float mb = fmaxf(fmaxf(fmaxf(d[0], d[1]), fmaxf(d[2], d[3])),
                               fmaxf(fmaxf(d[4], d[5]), fmaxf(d[6], d[7])));
        const float mn = fmaxf(m, mb);
        const float sc = __expf(m - mn);   // m=-inf on first batch -> sc=0

        float p[8];
        float ps = 0.f;
#pragma unroll
        for (int j = 0; j < 8; ++j) {
            p[j] = __expf(d[j] - mn);
            ps += p[j];
        }
        l = l * sc + ps;

        float ax = c0.x * sc, ay = c0.y * sc, az = c0.z * sc, aw = c0.w * sc;
#pragma unroll
        for (int j = 0; j < 8; ++j) {
            ax += p[j] * xa0[j].x; ay += p[j] * xa0[j].y;
            az += p[j] * xa0[j].z; aw += p[j] * xa0[j].w;
        }
        c0 = make_float4(ax, ay, az, aw);

        ax = c1.x * sc; ay = c1.y * sc; az = c1.z * sc; aw = c1.w * sc;
#pragma unroll
        for (int j = 0; j < 8; ++j) {
            ax += p[j] * xa1[j].x; ay += p[j] * xa1[j].y;
            az += p[j] * xa1[j].z; aw += p[j] * xa1[j].w;
        }
        c1 = make_float4(ax, ay, az, aw);

        m = mn;
    }

    *(float4*)&s_c[wv][lane * 4]       = c0;
    *(float4*)&s_c[wv][256 + lane * 4] = c1;
    if (lane == 0) { s_m[wv] = m; s_l[wv] = l; }
    __syncthreads();

    // ---------------- Merge 16 waves + normalize --------------------------
    float M = -INFINITY;
#pragma unroll
    for (int j = 0; j < NWAVE; ++j) M = fmaxf(M, s_m[j]);
    float L = 0.f;
    float alpha[NWAVE];
#pragma unroll
    for (int j = 0; j < NWAVE; ++j) {
        alpha[j] = __expf(s_m[j] - M);
        L += alpha[j] * s_l[j];
    }
    const float invL = 1.f / L;

    {   // two-stage alpha-weighted combine of 16 c-partials
        float cp = 0.f;
#pragma unroll
        for (int j = 0; j < 8; ++j) cp += alpha[half * 8 + j] * s_c[half * 8 + j][f5];
        s_p2[half][f5] = cp;
    }
    __syncthreads();
    if (tid < F) s_cf[tid] = (s_p2[0][tid] + s_p2[1][tid]) * invL;
    __syncthreads();

    // ---------------- out = cf @ Wv (half-split GEMV) ---------------------
    {
        const int fb = half * 256;
        float o0 = 0.f, o1 = 0.f, o2 = 0.f, o3 = 0.f;
#pragma unroll 4
        for (int f = 0; f < 256; f += 4) {
            o0 += s_cf[fb + f + 0] * Wv[(size_t)(fb + f + 0) * N + f5];
            o1 += s_cf[fb + f + 1] * Wv[(size_t)(fb + f + 1) * N + f5];
            o2 += s_cf[fb + f + 2] * Wv[(size_t)(fb + f + 2) * N + f5];
            o3 += s_cf[fb + f + 3] * Wv[(size_t)(fb + f + 3) * N + f5];
        }
        s_p2[half][f5] = (o0 + o1) + (o2 + o3);
    }
    __syncthreads();
    if (tid < N) out[(size_t)b * N + tid] = s_p2[0][tid] + s_p2[1][tid];
}

// -----------------------------------------------------------------------------
// Launcher.  Single fused launch; workspace unused.
// -----------------------------------------------------------------------------
extern "C" void kernel_launch(void* const* d_in, const int* in_sizes, int n_in,
                              void* d_out, int out_size, void* d_ws, size_t ws_size,
                              hipStream_t stream)
{
    const float* x    = (const float*)d_in[0];
    const float* Wk   = (const float*)d_in[1];
    const float* Wq   = (const float*)d_in[2];
    const float* Wv   = (const float*)d_in[3];
    const float* wvec = (const float*)d_in[4];
    float* out = (float*)d_out;

    fused_attn_kernel<<<B, 1024, 0, stream>>>(x, Wq, Wk, Wv, wvec, out);
}